// Round 10
// baseline (121.836 us; speedup 1.0000x reference)
//
#include <hip/hip_runtime.h>
#include <hip/hip_bf16.h>
#include <math.h>

// DCNv1 fused, bf16-MFMA, round 23: 16-wave mega-block, reduce2 deleted.
// r22 post-mortem: the graft bundle was -5.7us vs r15; prime suspect is the
// setprio removal (T5: helps when phases have wave role diversity - ours do).
// Verdict after 8 rounds: r15's per-phase body is a measured local optimum.
// r23 keeps that body BIT-IDENTICAL per wave (sampling task, wf loads after
// sampfma, LDS meta in issueg, setprio around MFMA, one barrier per phase)
// and deletes the K-split partial round trip instead:
//  * ONE 1024-thread block per (b,ho) row (grid 256, 16 waves/CU as before).
//    Waves = (ocg 0..7) x (kside 0..1); phase = 4 chunks; 18 phases = all 72
//    chunks in-block. Per-CU gather/wf/LDS/MFMA totals exactly r15's;
//    barriers per CU halve.
//  * reduce2 kernel GONE (-10us), partial writes GONE (41 -> ~17.5MB):
//    k-halves combine in a 2-round LDS epilogue (row stride 68 f32: 4*68=16
//    mod 32 -> quarter-waves alternate bank halves, 2-way = free) then
//    r20-validated float4 stores.

constexpr int B  = 4;
constexpr int C  = 256;
constexpr int H  = 64;
constexpr int W  = 64;
constexpr int OC = 256;
constexpr int Ho = 64;
constexpr int Wo = 64;

constexpr int NT     = 64;   // positions per block (full wo row)
constexpr int CHUNKS = 72;   // 2304 / 32
constexpr int WROW   = 40;   // padded s_col row (bf16): 80 B, quad-aligned
constexpr int XROW   = 40;   // prep_all's private LDS row pitch
constexpr int RSTR   = 68;   // epilogue red row stride (f32): 2-way banks

constexpr size_t WB_ELTS  = (size_t)CHUNKS * 16 * 512;    // 589824 ushorts
constexpr size_t XB_ELTS  = (size_t)B * 8 * 4096 * 32;    // 4194304 ushorts

typedef __attribute__((ext_vector_type(8))) short bf16x8;
typedef __attribute__((ext_vector_type(4))) float f32x4;

__device__ __forceinline__ float bf_lo(unsigned u) {
    union { unsigned i; float f; } c; c.i = u << 16; return c.f;
}
__device__ __forceinline__ float bf_hi(unsigned u) {
    union { unsigned i; float f; } c; c.i = u & 0xffff0000u; return c.f;
}
__device__ __forceinline__ ushort fbf(float f) {
    __hip_bfloat16 h = __float2bfloat16(f); return *(ushort*)&h;
}

// ---- fused pre-pass: blocks 0..1023 transpose x, blocks 1024..1279 do w ----
__global__ __launch_bounds__(256)
void prep_all(const float* __restrict__ x, const float* __restrict__ wt,
              ushort* __restrict__ xb, ushort* __restrict__ wB)
{
    __shared__ ushort sx[128 * XROW];         // x path: [hw][40]
    __shared__ ushort sw[CHUNKS * XROW];      // w path: [ch][40]
    const int t = threadIdx.x;

    if (blockIdx.x < 1024) {
        // ---- x: fp32 NCHW -> bf16 [b][cb][hw][c32] ----
        const int blk = blockIdx.x;           // (b*8+cb)*32 + hwb
        const int hwb = blk & 31;
        const int cb  = (blk >> 5) & 7;
        const int b   = blk >> 8;
        const int hw0 = hwb << 7;
        const int lhw = t & 127, chalf = t >> 7;
        #pragma unroll
        for (int i = 0; i < 16; ++i) {
            const int c = i * 2 + chalf;      // 0..31
            sx[lhw * XROW + c] =
                fbf(x[(((size_t)(b * 256 + cb * 32 + c)) << 12) + hw0 + lhw]);
        }
        __syncthreads();
        const int whw = t >> 1, wh = t & 1;   // 4 uint4 per 64-B hw row
        const uint4 v0 = *(const uint4*)&sx[whw * XROW + wh * 16];
        const uint4 v1 = *(const uint4*)&sx[whw * XROW + wh * 16 + 8];
        uint4* dst = (uint4*)(xb + ((size_t)((b * 8 + cb) * 4096 + hw0) << 5));
        dst[whw * 4 + wh * 2 + 0] = v0;
        dst[whw * 4 + wh * 2 + 1] = v1;
    } else {
        // ---- w: fp32 [oc][c][tap] -> bf16 fragment-order wB ----
        // wB piece (ch, og=oc>>4): 1024 B = 64 lanes x 16 B; lane l = kq*16+mr
        // holds {oc = og*16+mr, k = kq*8..kq*8+7 of chunk ch}.
        const int oc = blockIdx.x - 1024;
        const int c  = t, chb = c >> 5, kk = c & 31;
        const float* wp = wt + ((size_t)oc * C + c) * 9;
        #pragma unroll
        for (int tap = 0; tap < 9; ++tap)
            sw[(tap * 8 + chb) * XROW + kk] = fbf(wp[tap]);
        __syncthreads();
        const int og = oc >> 4, mr = oc & 15;
        for (int i = t; i < CHUNKS * 4; i += 256) {
            const int ch = i >> 2, kq = i & 3;
            *(uint4*)(wB + ((size_t)ch * 16 + og) * 512 + (kq * 16 + mr) * 8) =
                *(const uint4*)&sw[ch * XROW + kq * 8];
        }
    }
}

struct GathRegs { uint4 c00, c01, c10, c11; float4 mw; };

// ---------------- main fused kernel ----------------------------------------
__global__ __launch_bounds__(1024, 4)
void dcn_mfma(const ushort* __restrict__ xb, const float* __restrict__ off,
              const ushort* __restrict__ wB, float* __restrict__ out)
{
    // double-buffered col tiles: [buf][kc 0..3][pos*40 + k8*8]   (40960 B)
    __shared__ __align__(16) ushort s_col[2][4][NT * WROW];
    __shared__ __align__(16) float4 s_mw[9 * NT];            //  9216 B
    __shared__ __align__(8)  int2   s_midx[9 * NT];          //  4608 B

    // grid 256 = one block per (b,ho) row; b fixed per XCD.
    const int xcd = blockIdx.x & 7;
    const int b   = xcd & 3;
    const int ho  = ((xcd >> 2) << 5) + (blockIdx.x >> 3);
    const int tid = threadIdx.x;

    // ---- Phase A: bilinear meta per (tap, n); zero-fold padding into wts ----
    if (tid < 9 * NT) {
        const int n   = tid & 63;
        const int tap = tid >> 6;
        const float dy = off[((size_t)(b * 18 + 2 * tap)     * Ho + ho) * Wo + n];
        const float dx = off[((size_t)(b * 18 + 2 * tap + 1) * Ho + ho) * Wo + n];
        const float ph = (float)(ho - 1 + tap / 3) + dy;
        const float pw = (float)(n  - 1 + tap % 3) + dx;
        const float h0f = floorf(ph), w0f = floorf(pw);
        const int h0 = (int)h0f, w0 = (int)w0f;
        const float lh = ph - h0f, lw = pw - w0f;
        const int wb = min(max(w0, 0), W - 2);      // pair base stays in-plane
        const int ht = min(max(h0, 0), H - 1);
        const int hb = min(max(h0 + 1, 0), H - 1);
        const float s0 = (wb == w0) ? (1.f - lw) : ((wb == w0 + 1) ? lw : 0.f);
        const float s1 = (wb + 1 == w0 + 1) ? lw : ((wb + 1 == w0) ? (1.f - lw) : 0.f);
        const float wtp = (h0 >= 0 && h0 < H)         ? (1.f - lh) : 0.f;
        const float wbt = (h0 + 1 >= 0 && h0 + 1 < H) ? lh         : 0.f;
        s_midx[tid] = make_int2(ht * W + wb, hb * W + wb);
        s_mw[tid]   = make_float4(wtp * s0, wtp * s1, wbt * s0, wbt * s1);
    }

    const int lane = tid & 63;
    const int wv   = tid >> 6;        // 0..15
    const int ocg  = wv & 7;          // oc-group of 32
    const int kside= wv >> 3;         // which chunk-pair of the phase (MFMA)
    const int kq   = lane >> 4;
    const int mr   = lane & 15;

    // sampling task map: 1024 tasks = 4 chunks x 64 pos x 4 sgg per phase.
    const int kc_t = tid >> 8;        // which of the phase's 4 chunks (wave-uniform)
    const int st   = tid & 255;
    const int sn   = st >> 2;         // position 0..63
    const int sgg  = st & 3;          // channel octet (4 lanes = one 64B row)
    const ushort* xb_sg = xb + ((size_t)b << 20) + (sgg << 3);

    f32x4 acc[2][4];                  // [mt 16-oc][nt 16-pos]
    #pragma unroll
    for (int mt = 0; mt < 2; ++mt)
        #pragma unroll
        for (int nt = 0; nt < 4; ++nt)
            acc[mt][nt] = (f32x4){0.f, 0.f, 0.f, 0.f};

    auto issueg = [&](int p, GathRegs& g) {        // issue 4 corner gathers
        const int ch  = 4 * p + kc_t;
        const int tap = ch >> 3;
        const int cb  = ch & 7;
        const int2 mi = s_midx[tap * NT + sn];     // broadcast (4 lanes)
        g.mw = s_mw[tap * NT + sn];
        const ushort* xp = xb_sg + ((size_t)cb << 17);
        g.c00 = *(const uint4*)(xp + ((size_t)mi.x << 5));
        g.c01 = *(const uint4*)(xp + (((size_t)mi.x + 1) << 5));
        g.c10 = *(const uint4*)(xp + ((size_t)mi.y << 5));
        g.c11 = *(const uint4*)(xp + (((size_t)mi.y + 1) << 5));
    };
    auto sampfma = [&](const GathRegs& g, int buf) {
        union { ushort pk[8]; uint4 v; } u;
        const unsigned a00[4] = {g.c00.x, g.c00.y, g.c00.z, g.c00.w};
        const unsigned a01[4] = {g.c01.x, g.c01.y, g.c01.z, g.c01.w};
        const unsigned a10[4] = {g.c10.x, g.c10.y, g.c10.z, g.c10.w};
        const unsigned a11[4] = {g.c11.x, g.c11.y, g.c11.z, g.c11.w};
        #pragma unroll
        for (int j = 0; j < 4; ++j) {
            const float vlo = g.mw.x * bf_lo(a00[j]) + g.mw.y * bf_lo(a01[j])
                            + g.mw.z * bf_lo(a10[j]) + g.mw.w * bf_lo(a11[j]);
            const float vhi = g.mw.x * bf_hi(a00[j]) + g.mw.y * bf_hi(a01[j])
                            + g.mw.z * bf_hi(a10[j]) + g.mw.w * bf_hi(a11[j]);
            u.pk[2 * j]     = fbf(vlo);
            u.pk[2 * j + 1] = fbf(vhi);
        }
        *(uint4*)&s_col[buf][kc_t][sn * WROW + sgg * 8] = u.v;
    };
    // one phase = sample 4 chunks -> barrier -> 16 MFMAs (wave's chunk pair)
    auto phase = [&](int p, const GathRegs& gcur, int buf) {
        sampfma(gcur, buf);
        // A-frags after sampfma (r15 ordering): latency hides under
        // barrier + bfr reads.
        bf16x8 wf[2][2];
        const int chb = 4 * p + 2 * kside;
        #pragma unroll
        for (int kc = 0; kc < 2; ++kc)
            #pragma unroll
            for (int mt = 0; mt < 2; ++mt)
                wf[kc][mt] = *(const bf16x8*)
                    (wB + ((size_t)(chb + kc) * 16 + ocg * 2 + mt) * 512 + lane * 8);
        asm volatile("s_waitcnt lgkmcnt(0)" ::: "memory");  // ds_write visible
        __builtin_amdgcn_s_barrier();
        __builtin_amdgcn_sched_barrier(0);
        __builtin_amdgcn_s_setprio(1);
        #pragma unroll
        for (int kc = 0; kc < 2; ++kc)
            #pragma unroll
            for (int nt = 0; nt < 4; ++nt) {
                const bf16x8 bfr = *(const bf16x8*)
                    &s_col[buf][2 * kside + kc][(nt * 16 + mr) * WROW + kq * 8];
                #pragma unroll
                for (int mt = 0; mt < 2; ++mt)
                    acc[mt][nt] = __builtin_amdgcn_mfma_f32_16x16x32_bf16(
                        wf[kc][mt], bfr, acc[mt][nt], 0, 0, 0);
            }
        __builtin_amdgcn_s_setprio(0);
    };

    __syncthreads();                  // meta visible (only full drain)

    GathRegs gA, gB;
    issueg(0, gA);                    // prologue prefetch

    #pragma unroll 1
    for (int it = 0; it < 9; ++it) {  // 18 phases = 72 chunks
        issueg(2 * it + 1, gB);
        phase(2 * it, gA, 0);
        if (it < 8) issueg(2 * it + 2, gA);
        phase(2 * it + 1, gB, 1);
    }

    // ---- epilogue: combine k-halves in LDS (2 rounds), float4 stores ------
    // red[row][col]: row = ocg*16 + kq*4 + r (0..127), col = nt*16+mr (0..63),
    // row stride RSTR=68 f32 -> quarter-waves alternate bank halves (2-way).
    float* red = (float*)s_col;       // needs 128*68*4 = 34816 B <= 40960 B
    #pragma unroll 1
    for (int mt = 0; mt < 2; ++mt) {
        __syncthreads();              // loop LDS reads / prior round done
        if (kside == 1) {
            #pragma unroll
            for (int nt = 0; nt < 4; ++nt)
                #pragma unroll
                for (int r = 0; r < 4; ++r)
                    red[(ocg * 16 + kq * 4 + r) * RSTR + nt * 16 + mr] =
                        acc[mt][nt][r];
        }
        __syncthreads();
        if (kside == 0) {
            #pragma unroll
            for (int nt = 0; nt < 4; ++nt)
                #pragma unroll
                for (int r = 0; r < 4; ++r) {
                    const int a = (ocg * 16 + kq * 4 + r) * RSTR + nt * 16 + mr;
                    red[a] += acc[mt][nt][r];
                }
        }
        __syncthreads();
        // all 16 waves store: 128 rows x 16 float4 = 2048; 2 per thread.
        #pragma unroll
        for (int j = 0; j < 2; ++j) {
            const int fidx = (wv * 64 + lane) * 2 + j;
            const int rr = fidx >> 4, q = fidx & 15;
            const float4 v = *(const float4*)&red[rr * RSTR + q * 4];
            const int oc = (rr >> 4) * 32 + mt * 16 + (rr & 15);
            *(float4*)&out[(((size_t)(b * OC + oc) * Ho + ho) << 6) + q * 4] = v;
        }
    }
}

extern "C" void kernel_launch(void* const* d_in, const int* in_sizes, int n_in,
                              void* d_out, int out_size, void* d_ws, size_t ws_size,
                              hipStream_t stream)
{
    const float* x   = (const float*)d_in[0];
    const float* off = (const float*)d_in[1];
    const float* wt  = (const float*)d_in[2];
    float* out = (float*)d_out;

    ushort* wB = (ushort*)d_ws;                 // 1.18 MB
    ushort* xb = wB + WB_ELTS;                  // 8.39 MB

    prep_all<<<1280, 256, 0, stream>>>(x, wt, xb, wB);
    dcn_mfma<<<256, 1024, 0, stream>>>(xb, off, wB, out);
}